// Round 4
// baseline (1558.641 us; speedup 1.0000x reference)
//
#include <hip/hip_runtime.h>
#include <hip/hip_bf16.h>
#include <math.h>

#define NROWS 8192
#define DIM   1024
#define CAP   256
#define MARGIN 700.0f

using bf16x8 = __attribute__((ext_vector_type(8))) short;
using s16x4  = __attribute__((ext_vector_type(4))) short;
using f32x4  = __attribute__((ext_vector_type(4))) float;
typedef unsigned short u16;

// ---------------- Kernel S1: split X into hi/mid/lo bf16 planes ----------------
__global__ __launch_bounds__(256) void split_x(const float* __restrict__ X,
                                               u16* __restrict__ H,
                                               u16* __restrict__ M,
                                               u16* __restrict__ L) {
    const int idx = (blockIdx.x * 256 + threadIdx.x) * 4;
    float4 x = *(const float4*)&X[idx];
    float c[4] = {x.x, x.y, x.z, x.w};
    s16x4 h, m, l;
#pragma unroll
    for (int i = 0; i < 4; ++i) {
        __hip_bfloat16 hb = __float2bfloat16(c[i]);
        float r = c[i] - __bfloat162float(hb);
        __hip_bfloat16 mb = __float2bfloat16(r);
        float r2 = r - __bfloat162float(mb);
        __hip_bfloat16 lb = __float2bfloat16(r2);
        h[i] = *(short*)&hb; m[i] = *(short*)&mb; l[i] = *(short*)&lb;
    }
    *(s16x4*)&H[idx] = h;
    *(s16x4*)&M[idx] = m;
    *(s16x4*)&L[idx] = l;
}

// ---------------- Kernel S2: transpose + split W -> Wt planes [n][k] -----------
__global__ __launch_bounds__(256) void split_wt(const float* __restrict__ W0,
                                                const float* __restrict__ W1,
                                                const float* __restrict__ W2,
                                                u16* __restrict__ H0, u16* __restrict__ M0, u16* __restrict__ L0,
                                                u16* __restrict__ H1, u16* __restrict__ M1, u16* __restrict__ L1,
                                                u16* __restrict__ H2, u16* __restrict__ M2) {
    const int z = blockIdx.z;
    const float* W = (z == 0) ? W0 : (z == 1) ? W1 : W2;
    u16* H = (z == 0) ? H0 : (z == 1) ? H1 : H2;
    u16* M = (z == 0) ? M0 : (z == 1) ? M1 : M2;
    u16* L = (z == 0) ? L0 : (z == 1) ? L1 : nullptr;

    __shared__ float t[64][65];
    const int k0 = blockIdx.x * 64, n0 = blockIdx.y * 64;
    const int c = threadIdx.x & 63, r4 = threadIdx.x >> 6;   // c: 0..63, r4: 0..3
#pragma unroll
    for (int i = 0; i < 16; ++i) {
        int k = r4 + i * 4;
        t[k][c] = W[(size_t)(k0 + k) * DIM + n0 + c];        // coalesced along n
    }
    __syncthreads();
#pragma unroll
    for (int i = 0; i < 16; ++i) {
        int n = r4 + i * 4;
        float x = t[c][n];                                   // stride-65: conflict-free
        __hip_bfloat16 hb = __float2bfloat16(x);
        float r = x - __bfloat162float(hb);
        __hip_bfloat16 mb = __float2bfloat16(r);
        float r2 = r - __bfloat162float(mb);
        __hip_bfloat16 lb = __float2bfloat16(r2);
        const int o = (n0 + n) * DIM + k0 + c;               // coalesced along k
        H[o] = *(u16*)&hb;
        M[o] = *(u16*)&mb;
        if (L) L[o] = *(u16*)&lb;
    }
}

// ---------------- Kernel A: QKV via split-bf16 MFMA, barrier-free --------------
// C[8192x1024] = sum_p Xa_p @ Wt_p^T, 128x128 tile, 4 waves, no LDS.
// Register-pipelined fragment loads (depth 2): no __syncthreads in K-loop, so no
// vmcnt(0) drains — the R3 lesson. Products ordered small->large for fp32-acc
// rounding (mm, lh, hl, mh, hm, hh): Q/K element err ~1e-5 std.
__global__ __launch_bounds__(256) void qkv_mfma(
    const u16* __restrict__ Xh, const u16* __restrict__ Xm, const u16* __restrict__ Xl,
    const u16* __restrict__ Wh0, const u16* __restrict__ Wm0, const u16* __restrict__ Wl0,
    const u16* __restrict__ Wh1, const u16* __restrict__ Wm1, const u16* __restrict__ Wl1,
    const u16* __restrict__ Wh2, const u16* __restrict__ Wm2,
    float* __restrict__ Q, float* __restrict__ K,
    u16* __restrict__ Qb, u16* __restrict__ Kb, u16* __restrict__ Vb) {
    const int z = blockIdx.z;
    const u16* WH = (z == 0) ? Wh0 : (z == 1) ? Wh1 : Wh2;
    const u16* WM = (z == 0) ? Wm0 : (z == 1) ? Wm1 : Wm2;
    const u16* WL = (z == 0) ? Wl0 : (z == 1) ? Wl1 : nullptr;
    float* Out = (z == 0) ? Q : (z == 1) ? K : nullptr;
    u16* Outb  = (z == 0) ? Qb : (z == 1) ? Kb : Vb;
    const int np = (z == 2) ? 3 : 6;

    const int tid = threadIdx.x;
    const int w = tid >> 6, lane = tid & 63;
    const int wy = w >> 1, wx = w & 1;
    const int quad = lane >> 4, r16 = lane & 15;
    const int row0 = blockIdx.x * 128, col0 = blockIdx.y * 128;

    int aoff[4], boff[4];
#pragma unroll
    for (int m = 0; m < 4; ++m) aoff[m] = (row0 + wy * 64 + m * 16 + r16) * DIM + quad * 8;
#pragma unroll
    for (int n = 0; n < 4; ++n) boff[n] = (col0 + wx * 64 + n * 16 + r16) * DIM + quad * 8;

    f32x4 acc[4][4] = {};

    for (int p = 0; p < np; ++p) {
        // product order: z<2: mm, lh, hl, mh, hm, hh ; z==2 (V): hm, mh, hh
        int code = (z == 2) ? ((p == 0) ? 4 : (p == 1) ? 3 : 5) : p;
        const u16 *Ap, *Bp;
        switch (code) {
            case 0:  Ap = Xm; Bp = WM; break;   // mid*mid
            case 1:  Ap = Xl; Bp = WH; break;   // lo*hi
            case 2:  Ap = Xh; Bp = WL; break;   // hi*lo
            case 3:  Ap = Xm; Bp = WH; break;   // mid*hi
            case 4:  Ap = Xh; Bp = WM; break;   // hi*mid
            default: Ap = Xh; Bp = WH; break;   // hi*hi
        }
        bf16x8 a[2][4], b[2][4];
#pragma unroll
        for (int m = 0; m < 4; ++m) {
            a[0][m] = *(const bf16x8*)&Ap[aoff[m]];
            b[0][m] = *(const bf16x8*)&Bp[boff[m]];
        }
#pragma unroll 2
        for (int kk = 0; kk < 32; ++kk) {
            const int cur = kk & 1, nxt = 1 - cur;
            if (kk + 1 < 32) {
                const int ko = (kk + 1) * 32;
#pragma unroll
                for (int m = 0; m < 4; ++m) {
                    a[nxt][m] = *(const bf16x8*)&Ap[aoff[m] + ko];
                    b[nxt][m] = *(const bf16x8*)&Bp[boff[m] + ko];
                }
            }
#pragma unroll
            for (int m = 0; m < 4; ++m)
#pragma unroll
                for (int n = 0; n < 4; ++n)
                    acc[m][n] = __builtin_amdgcn_mfma_f32_16x16x32_bf16(a[cur][m], b[cur][n], acc[m][n], 0, 0, 0);
        }
    }

    // C/D layout: col = r16, row = quad*4 + reg (proven R1-R3)
#pragma unroll
    for (int m = 0; m < 4; ++m)
#pragma unroll
        for (int n = 0; n < 4; ++n)
#pragma unroll
            for (int reg = 0; reg < 4; ++reg) {
                const int row = row0 + wy * 64 + m * 16 + quad * 4 + reg;
                const int col = col0 + wx * 64 + n * 16 + r16;
                float v = acc[m][n][reg];
                if (Out) Out[row * DIM + col] = v;
                __hip_bfloat16 bb = __float2bfloat16(v);
                Outb[row * DIM + col] = *(u16*)&bb;
            }
}

// ---------------- Kernel B: barrier-free register-pipelined score --------------
__global__ __launch_bounds__(256) void score_kernel(const u16* __restrict__ Qb,
                                                    const u16* __restrict__ Kb,
                                                    int* __restrict__ cnt,
                                                    int2* __restrict__ cand) {
    const int tid = threadIdx.x;
    const int w = tid >> 6, lane = tid & 63;
    const int wy = w >> 1, wx = w & 1;
    const int quad = lane >> 4, r16 = lane & 15;

    // 8x8 super-tile swizzle (L2 locality)
    const int b = blockIdx.x;
    const int sb = b >> 6, within = b & 63;
    const int rowt = ((sb >> 3) << 3) | (within >> 3);
    const int colt = ((sb & 7) << 3) | (within & 7);
    const int row0 = rowt * 128, col0 = colt * 128;

    int aoff[4], boff[4];
#pragma unroll
    for (int m = 0; m < 4; ++m) aoff[m] = (row0 + wy * 64 + m * 16 + r16) * DIM + quad * 8;
#pragma unroll
    for (int n = 0; n < 4; ++n) boff[n] = (col0 + wx * 64 + n * 16 + r16) * DIM + quad * 8;

    f32x4 acc[4][4] = {};
    bf16x8 a[2][4], bb[2][4];
#pragma unroll
    for (int m = 0; m < 4; ++m) {
        a[0][m]  = *(const bf16x8*)&Qb[aoff[m]];
        bb[0][m] = *(const bf16x8*)&Kb[boff[m]];
    }
#pragma unroll 2
    for (int kk = 0; kk < 32; ++kk) {
        const int cur = kk & 1, nxt = 1 - cur;
        if (kk + 1 < 32) {
            const int ko = (kk + 1) * 32;
#pragma unroll
            for (int m = 0; m < 4; ++m) {
                a[nxt][m]  = *(const bf16x8*)&Qb[aoff[m] + ko];
                bb[nxt][m] = *(const bf16x8*)&Kb[boff[m] + ko];
            }
        }
#pragma unroll
        for (int m = 0; m < 4; ++m)
#pragma unroll
            for (int n = 0; n < 4; ++n)
                acc[m][n] = __builtin_amdgcn_mfma_f32_16x16x32_bf16(a[cur][m], bb[cur][n], acc[m][n], 0, 0, 0);
    }

    // Epilogue: per row: 64-col group max -> margin filter -> emit (proven R2/R3)
#pragma unroll
    for (int m = 0; m < 4; ++m) {
#pragma unroll
        for (int reg = 0; reg < 4; ++reg) {
            float mx = fmaxf(fmaxf(acc[m][0][reg], acc[m][1][reg]),
                             fmaxf(acc[m][2][reg], acc[m][3][reg]));
            mx = fmaxf(mx, __shfl_xor(mx, 1, 64));
            mx = fmaxf(mx, __shfl_xor(mx, 2, 64));
            mx = fmaxf(mx, __shfl_xor(mx, 4, 64));
            mx = fmaxf(mx, __shfl_xor(mx, 8, 64));
            const float th = mx - MARGIN;
            const int row = row0 + wy * 64 + m * 16 + quad * 4 + reg;
#pragma unroll
            for (int n = 0; n < 4; ++n) {
                float s = acc[m][n][reg];
                if (s >= th) {
                    int pos = atomicAdd(&cnt[row], 1);
                    if (pos < CAP)
                        cand[(size_t)row * CAP + pos] =
                            make_int2(col0 + wx * 64 + n * 16 + r16, __float_as_int(s));
                }
            }
        }
    }
}

// ---------------- Kernel E: exact sparse softmax + V gather --------------------
__global__ __launch_bounds__(256) void finalize_kernel(const float* __restrict__ Q,
                                                       const float* __restrict__ K,
                                                       const u16* __restrict__ Vb,
                                                       const int* __restrict__ cnt,
                                                       const int2* __restrict__ cand,
                                                       float* __restrict__ out) {
    const int i = blockIdx.x;
    const int tid = threadIdx.x;
    const int w = tid >> 6, lane = tid & 63;
    __shared__ float  red[256];
    __shared__ int    surv[64];
    __shared__ double sprec[64];
    __shared__ float  wgt[64];
    __shared__ int    nsurv;

    const int c = min(cnt[i], CAP);
    float m = -3.0e38f;
    for (int t = tid; t < c; t += 256)
        m = fmaxf(m, __int_as_float(cand[(size_t)i * CAP + t].y));
    red[tid] = m;
    __syncthreads();
    for (int s = 128; s > 0; s >>= 1) {
        if (tid < s) red[tid] = fmaxf(red[tid], red[tid + s]);
        __syncthreads();
    }
    const float th = red[0] - MARGIN;
    if (tid == 0) nsurv = 0;
    __syncthreads();
    for (int t = tid; t < c; t += 256) {
        int2 e = cand[(size_t)i * CAP + t];
        if (__int_as_float(e.y) >= th) {
            int p = atomicAdd(&nsurv, 1);
            if (p < 64) surv[p] = e.x;
        }
    }
    __syncthreads();
    const int ns = min(nsurv, 64);
    for (int u = w; u < ns; u += 4) {
        const int j = surv[u];
        double a = 0.0;
        for (int d = lane; d < DIM; d += 64)
            a += (double)Q[(size_t)i * DIM + d] * (double)K[(size_t)j * DIM + d];
#pragma unroll
        for (int o = 32; o > 0; o >>= 1)
            a += __shfl_down(a, o, 64);
        if (lane == 0) sprec[u] = a;
    }
    __syncthreads();
    if (tid == 0) {
        double mm = -1.0e300;
        for (int u = 0; u < ns; ++u) mm = fmax(mm, sprec[u]);
        double l = 0.0;
        for (int u = 0; u < ns; ++u) l += exp(sprec[u] - mm);
        for (int u = 0; u < ns; ++u) wgt[u] = (float)(exp(sprec[u] - mm) / l);
    }
    __syncthreads();
    for (int d = tid; d < DIM; d += 256) {
        float o = 0.f;
        for (int u = 0; u < ns; ++u) {
            __hip_bfloat16 bv = *(const __hip_bfloat16*)&Vb[(size_t)surv[u] * DIM + d];
            o += wgt[u] * __bfloat162float(bv);
        }
        out[(size_t)i * DIM + d] = o;
    }
}

extern "C" void kernel_launch(void* const* d_in, const int* in_sizes, int n_in,
                              void* d_out, int out_size, void* d_ws, size_t ws_size,
                              hipStream_t stream) {
    const float* X  = (const float*)d_in[0];
    const float* wq = (const float*)d_in[1];
    const float* wk = (const float*)d_in[2];
    const float* wv = (const float*)d_in[3];
    float* out = (float*)d_out;

    char* ws = (char*)d_ws;
    const size_t MB = 1024 * 1024;
    float* Q  = (float*)(ws);               // 32 MB
    float* K  = (float*)(ws + 32 * MB);     // 32 MB
    u16* Qb   = (u16*)(ws + 64 * MB);       // 16 MB
    u16* Kb   = (u16*)(ws + 80 * MB);       // 16 MB
    u16* Xh   = (u16*)(ws + 96 * MB);       // 16 MB
    u16* Xm   = (u16*)(ws + 112 * MB);      // 16 MB (cand aliases here post-QKV)
    u16* Xl   = (u16*)(ws + 128 * MB);      // 16 MB (cand tail aliases here)
    u16* Vb   = (u16*)(ws + 144 * MB);      // 16 MB
    u16* Wh0  = (u16*)(ws + 160 * MB);      // 8 x 2 MB of W^T planes
    u16* Wm0  = (u16*)(ws + 162 * MB);
    u16* Wl0  = (u16*)(ws + 164 * MB);
    u16* Wh1  = (u16*)(ws + 166 * MB);
    u16* Wm1  = (u16*)(ws + 168 * MB);
    u16* Wl1  = (u16*)(ws + 170 * MB);
    u16* Wh2  = (u16*)(ws + 172 * MB);
    u16* Wm2  = (u16*)(ws + 174 * MB);
    int* cnt  = (int*)(ws + 176 * MB);      // 32 KB
    int2* cand = (int2*)(ws + 112 * MB);    // 16.8 MB, aliases Xm/Xl (dead after qkv_mfma)

    hipMemsetAsync(cnt, 0, (size_t)NROWS * 4, stream);

    split_x<<<NROWS * DIM / 1024, 256, 0, stream>>>(X, Xh, Xm, Xl);
    split_wt<<<dim3(16, 16, 3), 256, 0, stream>>>(wq, wk, wv,
                                                  Wh0, Wm0, Wl0, Wh1, Wm1, Wl1, Wh2, Wm2);
    qkv_mfma<<<dim3(NROWS / 128, DIM / 128, 3), 256, 0, stream>>>(
        Xh, Xm, Xl, Wh0, Wm0, Wl0, Wh1, Wm1, Wl1, Wh2, Wm2, Q, K, Qb, Kb, Vb);

    score_kernel<<<4096, 256, 0, stream>>>(Qb, Kb, cnt, cand);

    finalize_kernel<<<NROWS, 256, 0, stream>>>(Q, K, Vb, cnt, cand, out);
}